// Round 2
// baseline (422.190 us; speedup 1.0000x reference)
//
#include <hip/hip_runtime.h>
#include <hip/hip_bf16.h>

// ResidualSSM: B=8, L=4096, D=1024. Channel c = d>>3 = kr*8 + j.
//   j < 4 : order-j differencing stencil (pascal[j], 4 taps) -> (d & 63) < 32.
//   j >= 4: moving-average residual, row r = kr*4+(j-4) of ma_r_kernel:
//           taps k[0]=1-1/w, k[1..w-1]=-1/w ->  y[t] = k0*x[t] + km*(S(t)-x[t]),
//           S(t) = sum_{s=t-w+1..t} x[s] (zero-padded)  -> (d & 63) >= 32.
// Dtype is self-detected from diff_kernel[0]==1.0 byte pattern (bf16 vs fp32);
// w is recovered exactly by binary search for the first zero tap.

namespace {
constexpr int B = 8, L = 4096, D = 1024;
constexpr int T_MA = 128;                         // time-tile per MA thread
constexpr int MA_TILES = L / T_MA;                // 32
constexpr int MA_THREADS = B * 512 * MA_TILES;    // 131072
constexpr int MA_BLOCKS = MA_THREADS / 256;       // 512
constexpr int DIFF_BLOCKS = B * (L / 8) * (512 / 32); // 65536
constexpr int TOTAL_BLOCKS = MA_BLOCKS + DIFF_BLOCKS;

template<bool BF>
__device__ __forceinline__ float ldx(const void* p, size_t i) {
    if constexpr (BF) return __bfloat162float(((const __hip_bfloat16*)p)[i]);
    else              return ((const float*)p)[i];
}
template<bool BF>
__device__ __forceinline__ void stx(void* p, size_t i, float v) {
    if constexpr (BF) ((__hip_bfloat16*)p)[i] = __float2bfloat16(v);
    else              ((float*)p)[i] = v;
}

template<bool BF>
__device__ __forceinline__ void run(const void* __restrict__ u,
                                    const void* __restrict__ dk,
                                    const void* __restrict__ mk,
                                    void* __restrict__ out,
                                    unsigned bx, int tid) {
    if (bx < (unsigned)MA_BLOCKS) {
        // ----- moving-average residual channels -----
        const int i    = bx * 256 + tid;
        const int m    = i & 511;                  // MA channel 0..511 (fastest: coalesced)
        const int tile = (i >> 9) & (MA_TILES - 1);
        const int b    = i >> 14;
        const int d    = ((m >> 5) << 6) + 32 + (m & 31);
        const int r    = m >> 3;                   // ma_r_kernel row

        const float k0 = ldx<BF>(mk, (size_t)r * 720 + 0);   // 1 - 1/w (as stored)
        const float km = ldx<BF>(mk, (size_t)r * 720 + 1);   // -1/w    (as stored)
        // w = first zero tap index; row is nonzero for tau<w, zero for tau>=w.
        int lo = 1, hi = 719;                      // mk[row,1]!=0 (w>=4), mk[row,719]==0 (w<=719)
        while (hi - lo > 1) {
            const int mid = (lo + hi) >> 1;
            if (ldx<BF>(mk, (size_t)r * 720 + mid) != 0.f) lo = mid; else hi = mid;
        }
        const int w = hi;

        const size_t base = (size_t)b * (L * D) + d;
        const int t0 = tile * T_MA;
        // halo warm-up: acc = sum_{s=max(0,t0-w)}^{t0-1} x[s]
        float acc = 0.f;
        int s0 = t0 - w; if (s0 < 0) s0 = 0;
        #pragma unroll 4
        for (int s = s0; s < t0; ++s)
            acc += ldx<BF>(u, base + (size_t)s * D);

        #pragma unroll 4
        for (int t = t0; t < t0 + T_MA; ++t) {
            const float xt = ldx<BF>(u, base + (size_t)t * D);
            acc += xt;                              // acc = sum [t-w, t] (clamped at 0)
            const int tl = t - w;
            if (tl >= 0) acc -= ldx<BF>(u, base + (size_t)tl * D);  // -> sum [t-w+1, t]
            stx<BF>(out, base + (size_t)t * D, k0 * xt + km * (acc - xt));
        }
    } else {
        // ----- differencing channels: <=4-tap causal stencil -----
        const unsigned bxx = bx - MA_BLOCKS;
        const int dl = tid & 31;
        const int tl = tid >> 5;
        const int gchunk = bxx & 15;
        const int tchunk = (bxx >> 4) & (L / 8 - 1);
        const int b      = bxx >> 13;
        const int d = (gchunk << 6) + dl;
        const int t = tchunk * 8 + tl;

        const int row = (gchunk << 2) + ((d >> 3) & 3);  // diff_kernel row kr*4+j
        const float c0 = ldx<BF>(dk, (size_t)row * 4 + 0);
        const float c1 = ldx<BF>(dk, (size_t)row * 4 + 1);
        const float c2 = ldx<BF>(dk, (size_t)row * 4 + 2);
        const float c3 = ldx<BF>(dk, (size_t)row * 4 + 3);

        const size_t p = ((size_t)b * L + t) * D + d;
        float acc = c0 * ldx<BF>(u, p);
        if (t >= 1) acc += c1 * ldx<BF>(u, p - D);
        if (t >= 2) acc += c2 * ldx<BF>(u, p - 2 * D);
        if (t >= 3) acc += c3 * ldx<BF>(u, p - 3 * D);
        stx<BF>(out, p, acc);
    }
}

__global__ __launch_bounds__(256)
void rssm_kernel(const void* __restrict__ u, const void* __restrict__ dk,
                 const void* __restrict__ mk, void* __restrict__ out) {
    // dtype probe: diff_kernel[0] == 1.0.
    // fp32 -> first dword 0x3F800000 ; bf16 [1.0, 0.0] -> first dword 0x00003F80.
    const unsigned w0 = *(const unsigned*)dk;
    const bool bf = (w0 == 0x00003F80u);
    if (bf) run<true >(u, dk, mk, out, blockIdx.x, threadIdx.x);
    else    run<false>(u, dk, mk, out, blockIdx.x, threadIdx.x);
}
}  // namespace

extern "C" void kernel_launch(void* const* d_in, const int* in_sizes, int n_in,
                              void* d_out, int out_size, void* d_ws, size_t ws_size,
                              hipStream_t stream) {
    rssm_kernel<<<TOTAL_BLOCKS, 256, 0, stream>>>(d_in[0], d_in[1], d_in[2], d_out);
}